// Round 17
// baseline (971.666 us; speedup 1.0000x reference)
//
#include <hip/hip_runtime.h>
#include <math.h>

#define NN 20000
#define NE 320000
#define NL 3
#define EPSV 1e-5f
#define MAXD 128
#define ASZ 2560    // 64*40 shorts
#define EPITCH 136  // e0 LDS tile pitch (shorts), 16B-aligned rows, 2-way banks

// f_stats layout (floats)
#define S_ESC  0
#define S_ESH  128
#define S_NSC  256
#define S_NSH  384
#define S_TOTAL 512

typedef __attribute__((ext_vector_type(8))) short bf16x8;
typedef __attribute__((ext_vector_type(4))) float f32x4;

__device__ __forceinline__ float sigf(float x) { return 1.0f / (1.0f + expf(-x)); }
__device__ __forceinline__ float b2f(unsigned short s) { return __uint_as_float((unsigned)s << 16); }
__device__ __forceinline__ unsigned short f2b(float a)
{
  unsigned u = __float_as_uint(a);
  return (unsigned short)((u + 0x7FFFu + ((u >> 16) & 1u)) >> 16);
}

// round-to-nearest-even split: a ~= h + l (both bf16)
__device__ __forceinline__ void bsplit(float a, unsigned short& h, unsigned short& l)
{
  unsigned u = __float_as_uint(a);
  unsigned rh = (u + 0x7FFFu + ((u >> 16) & 1u)) >> 16;
  h = (unsigned short)rh;
  float hf = __uint_as_float(rh << 16);
  float d = a - hf;
  unsigned v = __float_as_uint(d);
  l = (unsigned short)((v + 0x7FFFu + ((v >> 16) & 1u)) >> 16);
}

// ---- weight pre-split: src fp32 [nmat][k][c] -> dh/dl bf16 [nmat][c][k] (k-transposed) ----
__global__ __launch_bounds__(256) void prep_w(const float* __restrict__ src,
                                              unsigned short* __restrict__ dh,
                                              unsigned short* __restrict__ dl, int nmat)
{
  int idx = blockIdx.x * 256 + threadIdx.x;
  if (idx >= nmat * 16384) return;
  int m = idx >> 14, r = idx & 16383, k = r >> 7, c = r & 127;
  unsigned short h, l;
  bsplit(src[idx], h, l);
  long o = ((long)m << 14) + c * 128 + k;
  dh[o] = h; dl[o] = l;
}

// ==== staging helpers ====
__device__ __forceinline__ void loadWfrags(const unsigned short* __restrict__ Wh_g,
                                           const unsigned short* __restrict__ Wl_g,
                                           int k0, int w, int r16, int g8,
                                           bf16x8& h0, bf16x8& h1, bf16x8& l0, bf16x8& l1)
{
  long o0 = (long)(w * 32 + r16) * 128 + k0 + g8 * 8;
  long o1 = o0 + 16 * 128;
  h0 = *(const bf16x8*)(Wh_g + o0);
  h1 = *(const bf16x8*)(Wh_g + o1);
  l0 = *(const bf16x8*)(Wl_g + o0);
  l1 = *(const bf16x8*)(Wl_g + o1);
}
__device__ __forceinline__ void writeA_pair(const float4& a, int row, int c4,
                                            unsigned short* Ah, unsigned short* Al)
{
  unsigned short h0, l0, h1, l1, h2, l2, h3, l3;
  bsplit(a.x, h0, l0); bsplit(a.y, h1, l1); bsplit(a.z, h2, l2); bsplit(a.w, h3, l3);
  *(uint2*)(Ah + row * 40 + c4 * 4) =
      make_uint2((unsigned)h0 | ((unsigned)h1 << 16), (unsigned)h2 | ((unsigned)h3 << 16));
  *(uint2*)(Al + row * 40 + c4 * 4) =
      make_uint2((unsigned)l0 | ((unsigned)l1 << 16), (unsigned)l2 | ((unsigned)l3 << 16));
}
__device__ __forceinline__ void writeA_bf(const float4& a, int row, int c4, unsigned short* Ah)
{
  *(uint2*)(Ah + row * 40 + c4 * 4) = make_uint2(
      (unsigned)f2b(a.x) | ((unsigned)f2b(a.y) << 16),
      (unsigned)f2b(a.z) | ((unsigned)f2b(a.w) << 16));
}

// ---- MFMA frags: split A (3 MFMAs/cg), W in regs ----
__device__ __forceinline__ void mfma_frags3r(int r16, int g8, f32x4 acc[4][2],
    const unsigned short* Ah, const unsigned short* Al,
    bf16x8 wh0, bf16x8 wh1, bf16x8 wl0, bf16x8 wl1)
{
  bf16x8 ah[4], al[4];
  #pragma unroll
  for (int rg = 0; rg < 4; ++rg) {
    ah[rg] = *(const bf16x8*)(Ah + (rg * 16 + r16) * 40 + g8 * 8);
    al[rg] = *(const bf16x8*)(Al + (rg * 16 + r16) * 40 + g8 * 8);
  }
  #pragma unroll
  for (int rg = 0; rg < 4; ++rg) {
    acc[rg][0] = __builtin_amdgcn_mfma_f32_16x16x32_bf16(ah[rg], wh0, acc[rg][0], 0, 0, 0);
    acc[rg][0] = __builtin_amdgcn_mfma_f32_16x16x32_bf16(ah[rg], wl0, acc[rg][0], 0, 0, 0);
    acc[rg][0] = __builtin_amdgcn_mfma_f32_16x16x32_bf16(al[rg], wh0, acc[rg][0], 0, 0, 0);
    acc[rg][1] = __builtin_amdgcn_mfma_f32_16x16x32_bf16(ah[rg], wh1, acc[rg][1], 0, 0, 0);
    acc[rg][1] = __builtin_amdgcn_mfma_f32_16x16x32_bf16(ah[rg], wl1, acc[rg][1], 0, 0, 0);
    acc[rg][1] = __builtin_amdgcn_mfma_f32_16x16x32_bf16(al[rg], wh1, acc[rg][1], 0, 0, 0);
  }
}

// ---- MFMA frags: single-bf16 A (2 MFMAs/cg), W in regs ----
__device__ __forceinline__ void mfma_frags2r(int r16, int g8, f32x4 acc[4][2],
    const unsigned short* Ah,
    bf16x8 wh0, bf16x8 wh1, bf16x8 wl0, bf16x8 wl1)
{
  bf16x8 ah[4];
  #pragma unroll
  for (int rg = 0; rg < 4; ++rg)
    ah[rg] = *(const bf16x8*)(Ah + (rg * 16 + r16) * 40 + g8 * 8);
  #pragma unroll
  for (int rg = 0; rg < 4; ++rg) {
    acc[rg][0] = __builtin_amdgcn_mfma_f32_16x16x32_bf16(ah[rg], wh0, acc[rg][0], 0, 0, 0);
    acc[rg][0] = __builtin_amdgcn_mfma_f32_16x16x32_bf16(ah[rg], wl0, acc[rg][0], 0, 0, 0);
    acc[rg][1] = __builtin_amdgcn_mfma_f32_16x16x32_bf16(ah[rg], wh1, acc[rg][1], 0, 0, 0);
    acc[rg][1] = __builtin_amdgcn_mfma_f32_16x16x32_bf16(ah[rg], wl1, acc[rg][1], 0, 0, 0);
  }
}

#define ACC_INIT                          \
  _Pragma("unroll")                       \
  for (int rg = 0; rg < 4; ++rg)          \
    _Pragma("unroll")                     \
    for (int cg = 0; cg < 2; ++cg)        \
      acc[rg][cg] = (f32x4){0.f, 0.f, 0.f, 0.f};

// ---- core, fp32 input (split-A); W 2-stage from L2 ----
__device__ __forceinline__ void mfma_core_f32(
    const float* __restrict__ A, long base, int M,
    const unsigned short* __restrict__ Wh_g, const unsigned short* __restrict__ Wl_g,
    int tid, f32x4 acc[4][2], unsigned short* Ah, unsigned short* Al)
{
  int lane = tid & 63, w = tid >> 6, r16 = lane & 15, g8 = lane >> 4;
  int r0 = tid >> 3, c4 = tid & 7;
  long g0 = base + r0, g1 = g0 + 32;
  bool v0 = g0 < M, v1 = g1 < M;
  ACC_INIT
  float4 a[4][2];
  #pragma unroll
  for (int ks = 0; ks < 4; ++ks) {
    a[ks][0] = v0 ? *(const float4*)(A + g0 * 128 + ks * 32 + c4 * 4) : make_float4(0.f, 0.f, 0.f, 0.f);
    a[ks][1] = v1 ? *(const float4*)(A + g1 * 128 + ks * 32 + c4 * 4) : make_float4(0.f, 0.f, 0.f, 0.f);
  }
  bf16x8 wc0, wc1, wc2, wc3, wn0, wn1, wn2, wn3;
  loadWfrags(Wh_g, Wl_g, 0, w, r16, g8, wc0, wc1, wc2, wc3);
  writeA_pair(a[0][0], r0, c4, Ah, Al);
  writeA_pair(a[0][1], r0 + 32, c4, Ah, Al);
  #pragma unroll
  for (int ks = 0; ks < 4; ++ks) {
    __syncthreads();
    int cb = ks & 1, nb = cb ^ 1;
    if (ks < 3) loadWfrags(Wh_g, Wl_g, 32 * (ks + 1), w, r16, g8, wn0, wn1, wn2, wn3);
    mfma_frags3r(r16, g8, acc, Ah + cb * ASZ, Al + cb * ASZ, wc0, wc1, wc2, wc3);
    if (ks < 3) {
      writeA_pair(a[ks + 1][0], r0, c4, Ah + nb * ASZ, Al + nb * ASZ);
      writeA_pair(a[ks + 1][1], r0 + 32, c4, Ah + nb * ASZ, Al + nb * ASZ);
      wc0 = wn0; wc1 = wn1; wc2 = wn2; wc3 = wn3;
    }
  }
}

// ---- core, fp32 sequential rows -> bf16-A (2 MFMA); W 2-stage ----
__device__ __forceinline__ void mfma_core_bf16f(
    const float* __restrict__ A, long base,
    const unsigned short* __restrict__ Wh_g, const unsigned short* __restrict__ Wl_g,
    int tid, f32x4 acc[4][2], unsigned short* Ah)
{
  int lane = tid & 63, w = tid >> 6, r16 = lane & 15, g8 = lane >> 4;
  int r0 = tid >> 3, c4 = tid & 7;
  long g0 = base + r0, g1 = g0 + 32;
  ACC_INIT
  float4 a[4][2];
  #pragma unroll
  for (int ks = 0; ks < 4; ++ks) {
    a[ks][0] = *(const float4*)(A + g0 * 128 + ks * 32 + c4 * 4);
    a[ks][1] = *(const float4*)(A + g1 * 128 + ks * 32 + c4 * 4);
  }
  bf16x8 wc0, wc1, wc2, wc3, wn0, wn1, wn2, wn3;
  loadWfrags(Wh_g, Wl_g, 0, w, r16, g8, wc0, wc1, wc2, wc3);
  writeA_bf(a[0][0], r0, c4, Ah);
  writeA_bf(a[0][1], r0 + 32, c4, Ah);
  #pragma unroll
  for (int ks = 0; ks < 4; ++ks) {
    __syncthreads();
    int cb = ks & 1, nb = cb ^ 1;
    if (ks < 3) loadWfrags(Wh_g, Wl_g, 32 * (ks + 1), w, r16, g8, wn0, wn1, wn2, wn3);
    mfma_frags2r(r16, g8, acc, Ah + cb * ASZ, wc0, wc1, wc2, wc3);
    if (ks < 3) {
      writeA_bf(a[ks + 1][0], r0, c4, Ah + nb * ASZ);
      writeA_bf(a[ks + 1][1], r0 + 32, c4, Ah + nb * ASZ);
      wc0 = wn0; wc1 = wn1; wc2 = wn2; wc3 = wn3;
    }
  }
}

// ---- core, fused edge update: e_new = e + relu(sc*ehat + sh); ALL chunks prefetched ----
template<bool WB>
__device__ __forceinline__ void mfma_core_upd(
    unsigned short* __restrict__ Ebf,
    const unsigned short* __restrict__ EHAT, long base,
    const unsigned short* __restrict__ Wh_g, const unsigned short* __restrict__ Wl_g,
    const float* s_sc, const float* s_sh,
    int tid, f32x4 acc[4][2], unsigned short* Ah)
{
  int lane = tid & 63, w = tid >> 6, r16 = lane & 15, g8 = lane >> 4;
  int row = tid >> 2, q = tid & 3;
  ACC_INIT
  long grow = (base + row) * 128;
  uint4 ev[4], hv[4];
  #pragma unroll
  for (int ks = 0; ks < 4; ++ks) {
    ev[ks] = *(const uint4*)(Ebf + grow + ks * 32 + q * 8);
    hv[ks] = *(const uint4*)(EHAT + grow + ks * 32 + q * 8);
  }
  bf16x8 wc0, wc1, wc2, wc3, wn0, wn1, wn2, wn3;
  loadWfrags(Wh_g, Wl_g, 0, w, r16, g8, wc0, wc1, wc2, wc3);

  #pragma unroll
  for (int ks = 0; ks < 4; ++ks) {
    int cb = ks & 1;
    int cbase = ks * 32 + q * 8;
    {
      uint4 evk = ev[ks], hvk = hv[ks];
      unsigned es[8] = {evk.x & 0xFFFFu, evk.x >> 16, evk.y & 0xFFFFu, evk.y >> 16,
                        evk.z & 0xFFFFu, evk.z >> 16, evk.w & 0xFFFFu, evk.w >> 16};
      unsigned hs[8] = {hvk.x & 0xFFFFu, hvk.x >> 16, hvk.y & 0xFFFFu, hvk.y >> 16,
                        hvk.z & 0xFFFFu, hvk.z >> 16, hvk.w & 0xFFFFu, hvk.w >> 16};
      unsigned short nv[8];
      #pragma unroll
      for (int i = 0; i < 8; ++i) {
        float v = b2f((unsigned short)es[i]) +
                  fmaxf(fmaf(s_sc[cbase + i], b2f((unsigned short)hs[i]), s_sh[cbase + i]), 0.f);
        nv[i] = f2b(v);
      }
      uint4 nq = make_uint4((unsigned)nv[0] | ((unsigned)nv[1] << 16),
                            (unsigned)nv[2] | ((unsigned)nv[3] << 16),
                            (unsigned)nv[4] | ((unsigned)nv[5] << 16),
                            (unsigned)nv[6] | ((unsigned)nv[7] << 16));
      *(uint4*)(Ah + cb * ASZ + row * 40 + q * 8) = nq;
      if (WB) *(uint4*)(Ebf + grow + cbase) = nq;
    }
    __syncthreads();
    if (ks < 3) loadWfrags(Wh_g, Wl_g, 32 * (ks + 1), w, r16, g8, wn0, wn1, wn2, wn3);
    mfma_frags2r(r16, g8, acc, Ah + cb * ASZ, wc0, wc1, wc2, wc3);
    if (ks < 3) { wc0 = wn0; wc1 = wn1; wc2 = wn2; wc3 = wn3; }
    if (ks < 2) __syncthreads();
  }
}

// ---- shared edge epilogue (slot-space, sequential): ehat bf16 + BN partials ----
__device__ __forceinline__ void edge_epilogue(
    f32x4 acc[4][2], const float* __restrict__ bias,
    const int* __restrict__ srcp, const int* __restrict__ dstp,
    const float* __restrict__ Dh, const float* __restrict__ Eh,
    unsigned short* __restrict__ ehat, float* __restrict__ epart, int do_stats,
    long base, int tid)
{
  int lane = tid & 63, w = tid >> 6;
  int r16 = lane & 15, g8 = lane >> 4;
  int colA = w * 32 + r16, colB = colA + 16;
  float bA = bias[colA], bB = bias[colB];
  float s0 = 0.f, s1 = 0.f, q0 = 0.f, q1 = 0.f;
  #pragma unroll
  for (int rg = 0; rg < 4; ++rg)
    #pragma unroll
    for (int j = 0; j < 4; ++j) {
      long erow = base + rg * 16 + g8 * 4 + j;  // NE multiple of 64
      int si = srcp[erow], di = dstp[erow];
      const float* dhp = Dh + (long)di * 128;
      const float* ehp = Eh + (long)si * 128;
      float xA = acc[rg][0][j] + bA + dhp[colA] + ehp[colA];
      float xB = acc[rg][1][j] + bB + dhp[colB] + ehp[colB];
      ehat[erow * 128 + colA] = f2b(xA);
      ehat[erow * 128 + colB] = f2b(xB);
      s0 += xA; q0 += xA * xA; s1 += xB; q1 += xB * xB;
    }
  if (do_stats) {
    s0 += __shfl_xor(s0, 16); s0 += __shfl_xor(s0, 32);
    q0 += __shfl_xor(q0, 16); q0 += __shfl_xor(q0, 32);
    s1 += __shfl_xor(s1, 16); s1 += __shfl_xor(s1, 32);
    q1 += __shfl_xor(q1, 16); q1 += __shfl_xor(q1, 32);
    if (g8 == 0) {
      float* bp = epart + (long)blockIdx.x * 256;
      bp[colA] = s0;       bp[128 + colA] = q0;
      bp[colB] = s1;       bp[128 + colB] = q1;
    }
  }
}

// ---- C[M,128] = A @ W + b (fp32 out) ----
__global__ __launch_bounds__(256) void gemm128(
    const float* __restrict__ A, const unsigned short* __restrict__ Wh_g,
    const unsigned short* __restrict__ Wl_g, const float* __restrict__ bias,
    float* __restrict__ C, int M)
{
  __shared__ unsigned short Ah[2 * ASZ], Al[2 * ASZ];
  int tid = threadIdx.x, lane = tid & 63, w = tid >> 6;
  int r16 = lane & 15, g8 = lane >> 4;
  long base = (long)blockIdx.x * 64;
  f32x4 acc[4][2];
  mfma_core_f32(A, base, M, Wh_g, Wl_g, tid, acc, Ah, Al);
  #pragma unroll
  for (int cg = 0; cg < 2; ++cg) {
    int col = w * 32 + cg * 16 + r16;
    float b = bias[col];
    #pragma unroll
    for (int rg = 0; rg < 4; ++rg)
      #pragma unroll
      for (int j = 0; j < 4; ++j) {
        long row = base + rg * 16 + g8 * 4 + j;
        if (row < M) C[row * 128 + col] = acc[rg][cg][j] + b;
      }
  }
}

// ---- 4 node GEMMs (A,B,D,E) in one launch ----
__global__ __launch_bounds__(256) void gemm128_x4(
    const float* __restrict__ A, const unsigned short* __restrict__ Wh_l,
    const unsigned short* __restrict__ Wl_l, const float* __restrict__ bl,
    float* __restrict__ o0, float* __restrict__ o1, float* __restrict__ o2,
    float* __restrict__ o3, int M)
{
  __shared__ unsigned short Ah[2 * ASZ], Al[2 * ASZ];
  int y = blockIdx.y;
  int widx = (y < 2) ? y : y + 1;  // {0,1,3,4}
  const unsigned short* Wh_g = Wh_l + ((long)widx << 14);
  const unsigned short* Wl_g = Wl_l + ((long)widx << 14);
  const float* bias = bl + (long)widx * 128;
  float* C = (y == 0) ? o0 : (y == 1) ? o1 : (y == 2) ? o2 : o3;
  int tid = threadIdx.x, lane = tid & 63, w = tid >> 6;
  int r16 = lane & 15, g8 = lane >> 4;
  long base = (long)blockIdx.x * 64;
  f32x4 acc[4][2];
  mfma_core_f32(A, base, M, Wh_g, Wl_g, tid, acc, Ah, Al);
  #pragma unroll
  for (int cg = 0; cg < 2; ++cg) {
    int col = w * 32 + cg * 16 + r16;
    float b = bias[col];
    #pragma unroll
    for (int rg = 0; rg < 4; ++rg)
      #pragma unroll
      for (int j = 0; j < 4; ++j) {
        long row = base + rg * 16 + g8 * 4 + j;
        if (row < M) C[row * 128 + col] = acc[rg][cg][j] + b;
      }
  }
}

// ---- layer-0 mega kernel (ORIGINAL edge order): emb GEMM (seq eattr) -> e_bf[slot]
//      -> Ce GEMM from LDS e0 tile -> ehat[slot] + BN partials ----
__global__ __launch_bounds__(256) void edge_emb_fused0(
    const float* __restrict__ eattr,
    const unsigned short* __restrict__ Weh, const unsigned short* __restrict__ Wel,
    const float* __restrict__ be,
    const unsigned short* __restrict__ Wch, const unsigned short* __restrict__ Wcl,
    const float* __restrict__ bc,
    const int* __restrict__ osrc, const int* __restrict__ odst, const int* __restrict__ slot,
    const float* __restrict__ Dh, const float* __restrict__ Eh,
    unsigned short* __restrict__ e_bf, unsigned short* __restrict__ ehat,
    float* __restrict__ epart)
{
  __shared__ unsigned short Ah[2 * ASZ];
  __shared__ unsigned short E0[64 * EPITCH];
  __shared__ int sslot[64];
  int tid = threadIdx.x, lane = tid & 63, w = tid >> 6;
  int r16 = lane & 15, g8 = lane >> 4;
  long base = (long)blockIdx.x * 64;
  if (tid < 64) sslot[tid] = slot[base + tid];  // covered by core's first barrier
  f32x4 acc[4][2];
  // phase 1: emb GEMM (A = bf16(eattr) sequential, W = We split)
  mfma_core_bf16f(eattr, base, Weh, Wel, tid, acc, Ah);
  // phase 2: +bias -> e_bf[slot] (scattered) + stage e0 tile in LDS
  #pragma unroll
  for (int cg = 0; cg < 2; ++cg) {
    int col = w * 32 + cg * 16 + r16;
    float b = be[col];
    #pragma unroll
    for (int rg = 0; rg < 4; ++rg)
      #pragma unroll
      for (int j = 0; j < 4; ++j) {
        int row = rg * 16 + g8 * 4 + j;
        unsigned short bv = f2b(acc[rg][cg][j] + b);
        E0[row * EPITCH + col] = bv;
        e_bf[(long)sslot[row] * 128 + col] = bv;
      }
  }
  __syncthreads();
  // phase 3: Ce GEMM from E0 (k over 4 chunks), W = Wc split
  ACC_INIT
  #pragma unroll
  for (int ks = 0; ks < 4; ++ks) {
    bf16x8 wh0, wh1, wl0, wl1;
    loadWfrags(Wch, Wcl, ks * 32, w, r16, g8, wh0, wh1, wl0, wl1);
    bf16x8 ah[4];
    #pragma unroll
    for (int rg = 0; rg < 4; ++rg)
      ah[rg] = *(const bf16x8*)(E0 + (rg * 16 + r16) * EPITCH + ks * 32 + g8 * 8);
    #pragma unroll
    for (int rg = 0; rg < 4; ++rg) {
      acc[rg][0] = __builtin_amdgcn_mfma_f32_16x16x32_bf16(ah[rg], wh0, acc[rg][0], 0, 0, 0);
      acc[rg][0] = __builtin_amdgcn_mfma_f32_16x16x32_bf16(ah[rg], wl0, acc[rg][0], 0, 0, 0);
      acc[rg][1] = __builtin_amdgcn_mfma_f32_16x16x32_bf16(ah[rg], wh1, acc[rg][1], 0, 0, 0);
      acc[rg][1] = __builtin_amdgcn_mfma_f32_16x16x32_bf16(ah[rg], wl1, acc[rg][1], 0, 0, 0);
    }
  }
  // phase 4: epilogue (original-order indices; scattered ehat store; stats always on)
  int colA = w * 32 + r16, colB = colA + 16;
  float bA = bc[colA], bB = bc[colB];
  float s0 = 0.f, s1 = 0.f, q0 = 0.f, q1 = 0.f;
  #pragma unroll
  for (int rg = 0; rg < 4; ++rg)
    #pragma unroll
    for (int j = 0; j < 4; ++j) {
      int row = rg * 16 + g8 * 4 + j;
      long erow = base + row;
      int si = osrc[erow], di = odst[erow];
      const float* dhp = Dh + (long)di * 128;
      const float* ehp = Eh + (long)si * 128;
      float xA = acc[rg][0][j] + bA + dhp[colA] + ehp[colA];
      float xB = acc[rg][1][j] + bB + dhp[colB] + ehp[colB];
      long srow = sslot[row];
      ehat[srow * 128 + colA] = f2b(xA);
      ehat[srow * 128 + colB] = f2b(xB);
      s0 += xA; q0 += xA * xA; s1 += xB; q1 += xB * xB;
    }
  s0 += __shfl_xor(s0, 16); s0 += __shfl_xor(s0, 32);
  q0 += __shfl_xor(q0, 16); q0 += __shfl_xor(q0, 32);
  s1 += __shfl_xor(s1, 16); s1 += __shfl_xor(s1, 32);
  q1 += __shfl_xor(q1, 16); q1 += __shfl_xor(q1, 32);
  if (g8 == 0) {
    float* bp = epart + (long)blockIdx.x * 256;
    bp[colA] = s0;       bp[128 + colA] = q0;
    bp[colB] = s1;       bp[128 + colB] = q1;
  }
}

// ---- edge_fused layers 1,2: fused e-update staging + GEMM + epilogue ----
template<bool WB>
__global__ __launch_bounds__(256) void edge_fusedU(
    unsigned short* __restrict__ ebf,
    unsigned short* __restrict__ ehat,
    const float* __restrict__ scale, const float* __restrict__ shift,
    const unsigned short* __restrict__ Wh_g, const unsigned short* __restrict__ Wl_g,
    const float* __restrict__ bias, const int* __restrict__ srcp, const int* __restrict__ dstp,
    const float* __restrict__ Dh, const float* __restrict__ Eh,
    float* __restrict__ epart, int do_stats)
{
  __shared__ unsigned short Ah[2 * ASZ];
  __shared__ float s_sc[128], s_sh[128];
  int tid = threadIdx.x;
  if (tid < 128) { s_sc[tid] = scale[tid]; s_sh[tid] = shift[tid]; }
  __syncthreads();
  long base = (long)blockIdx.x * 64;
  f32x4 acc[4][2];
  mfma_core_upd<WB>(ebf, ehat, base, Wh_g, Wl_g, s_sc, s_sh, tid, acc, Ah);
  edge_epilogue(acc, bias, srcp, dstp, Dh, Eh, ehat, epart, do_stats, base, tid);
}

// ---- generic partial reduce ----
__global__ __launch_bounds__(256) void reduce_part(const float* __restrict__ in,
                                                   float* __restrict__ outp, int groups)
{
  int t = threadIdx.x;
  long base = (long)blockIdx.x * groups * 256;
  float acc = 0.f;
  for (int i = 0; i < groups; ++i) acc += in[base + i * 256 + t];
  outp[(long)blockIdx.x * 256 + t] = acc;
}

__global__ void finalize_bn_p(const float* __restrict__ part, int np, float invn,
                              const float* __restrict__ gamma, const float* __restrict__ beta,
                              float* __restrict__ scale, float* __restrict__ shift)
{
  int c = threadIdx.x;  // 128
  float s = 0.f, q = 0.f;
  for (int p = 0; p < np; ++p) {
    s += part[(long)p * 256 + c];
    q += part[(long)p * 256 + 128 + c];
  }
  float mu = s * invn;
  float var = q * invn - mu * mu;
  float sc = gamma[c] * rsqrtf(var + EPSV);
  scale[c] = sc;
  shift[c] = beta[c] - sc * mu;
}

// ==================== CSR build (by dst) ====================
__global__ __launch_bounds__(256) void hist_dst(const int* __restrict__ dst, int* __restrict__ deg)
{
  int e = blockIdx.x * 256 + threadIdx.x;
  if (e < NE) atomicAdd(&deg[dst[e]], 1);
}

__global__ __launch_bounds__(1024) void scan_deg(const int* __restrict__ deg,
                                                 int* __restrict__ rowstart, int* __restrict__ cursor)
{
  __shared__ int wsum[16];
  __shared__ int carry;
  int tid = threadIdx.x, lane = tid & 63, wid = tid >> 6;
  if (tid == 0) carry = 0;
  __syncthreads();
  for (int base = 0; base < NN; base += 1024) {
    int i = base + tid;
    int v = (i < NN) ? deg[i] : 0;
    int x = v;
    #pragma unroll
    for (int off = 1; off < 64; off <<= 1) {
      int y = __shfl_up(x, off, 64);
      if (lane >= off) x += y;
    }
    if (lane == 63) wsum[wid] = x;
    __syncthreads();
    int wpref = 0;
    for (int j = 0; j < wid; ++j) wpref += wsum[j];
    int excl = carry + wpref + x - v;
    if (i < NN) { rowstart[i] = excl; cursor[i] = excl; }
    __syncthreads();
    if (tid == 1023) carry = excl + v;
    __syncthreads();
  }
  if (tid == 0) rowstart[NN] = NE;
}

__global__ __launch_bounds__(256) void fill_csr(const int* __restrict__ dst,
                                                int* __restrict__ cursor, int* __restrict__ elist)
{
  int e = blockIdx.x * 256 + threadIdx.x;
  if (e < NE) {
    int p = atomicAdd(&cursor[dst[e]], 1);
    elist[p] = e;
  }
}

// ---- deterministic order: sort each node's segment by edge id ----
__global__ __launch_bounds__(128) void seg_sort(const int* __restrict__ rowstart,
                                                int* __restrict__ elist)
{
  __shared__ int buf[MAXD];
  __shared__ int srt[MAXD];
  int n = blockIdx.x;
  int s = rowstart[n], t = rowstart[n + 1];
  int deg = t - s;
  if (deg > MAXD) deg = MAXD;
  int tid = threadIdx.x;
  if (tid < deg) buf[tid] = elist[s + tid];
  __syncthreads();
  if (tid < deg) {
    int v = buf[tid], r = 0;
    for (int j = 0; j < deg; ++j) r += (buf[j] < v);
    srt[r] = v;
  }
  __syncthreads();
  if (tid < deg) elist[s + tid] = srt[tid];
}

// ---- permuted src/dst arrays (slot space) + inverse permutation ----
__global__ __launch_bounds__(256) void perm_edges(const int* __restrict__ elist,
                                                  const int* __restrict__ src,
                                                  const int* __restrict__ dst,
                                                  int* __restrict__ srcp, int* __restrict__ dstp,
                                                  int* __restrict__ slot)
{
  int s = blockIdx.x * 256 + threadIdx.x;
  if (s < NE) {
    int e = elist[s];
    srcp[s] = src[e];
    dstp[s] = dst[e];
    slot[e] = s;
  }
}

// ---- per-node gather, CSR-contiguous; ehat is bf16 ----
__global__ __launch_bounds__(128) void gather_node(
    const unsigned short* __restrict__ ehat, const float* __restrict__ Bh,
    const int* __restrict__ srcp, const int* __restrict__ rowstart, float* __restrict__ x)
{
  __shared__ int ssrc[MAXD];
  int n = blockIdx.x;
  int s = rowstart[n], t = rowstart[n + 1];
  int deg = t - s;
  int nload = deg < MAXD ? deg : MAXD;
  int tid = threadIdx.x;
  if (tid < nload) ssrc[tid] = srcp[s + tid];
  __syncthreads();
  float acc = 0.f;
  for (int k = 0; k < nload; ++k)
    acc += sigf(b2f(ehat[(long)(s + k) * 128 + tid])) * Bh[(long)ssrc[k] * 128 + tid];
  for (int k = MAXD; k < deg; ++k)
    acc += sigf(b2f(ehat[(long)(s + k) * 128 + tid])) * Bh[(long)srcp[s + k] * 128 + tid];
  x[(long)n * 128 + tid] += acc;
}

// ---- node BN partials: 250 blocks x 80 rows ----
__global__ __launch_bounds__(256) void stats128p(const float* __restrict__ x, float* __restrict__ part)
{
  __shared__ float red[8][32][8];
  int tid = threadIdx.x, tx = tid & 31, ty = tid >> 5;
  long rbase = (long)blockIdx.x * 80;
  float a0 = 0, a1 = 0, a2 = 0, a3 = 0, c0 = 0, c1 = 0, c2 = 0, c3 = 0;
  #pragma unroll
  for (int i = 0; i < 10; ++i) {
    long row = rbase + i * 8 + ty;
    float4 v = *(const float4*)(x + row * 128 + tx * 4);
    a0 += v.x; a1 += v.y; a2 += v.z; a3 += v.w;
    c0 += v.x * v.x; c1 += v.y * v.y; c2 += v.z * v.z; c3 += v.w * v.w;
  }
  red[ty][tx][0] = a0; red[ty][tx][1] = a1; red[ty][tx][2] = a2; red[ty][tx][3] = a3;
  red[ty][tx][4] = c0; red[ty][tx][5] = c1; red[ty][tx][6] = c2; red[ty][tx][7] = c3;
  __syncthreads();
  if (ty == 0) {
    float b0 = 0, b1 = 0, b2 = 0, b3 = 0, d0 = 0, d1 = 0, d2 = 0, d3 = 0;
    #pragma unroll
    for (int t = 0; t < 8; ++t) {
      b0 += red[t][tx][0]; b1 += red[t][tx][1]; b2 += red[t][tx][2]; b3 += red[t][tx][3];
      d0 += red[t][tx][4]; d1 += red[t][tx][5]; d2 += red[t][tx][6]; d3 += red[t][tx][7];
    }
    float* bp = part + (long)blockIdx.x * 256;
    bp[tx * 4 + 0] = b0; bp[tx * 4 + 1] = b1; bp[tx * 4 + 2] = b2; bp[tx * 4 + 3] = b3;
    bp[128 + tx * 4 + 0] = d0; bp[128 + tx * 4 + 1] = d1;
    bp[128 + tx * 4 + 2] = d2; bp[128 + tx * 4 + 3] = d3;
  }
}

// ---- node pass 2: h += relu(bn(x)) ----
__global__ __launch_bounds__(256) void pass2(
    float* __restrict__ dsta, const float* __restrict__ xv,
    const float* __restrict__ scale, const float* __restrict__ shift, long n4)
{
  long i = (long)blockIdx.x * 256 + threadIdx.x;
  if (i >= n4) return;
  int c = (int)(i & 31) * 4;
  float4 x = ((const float4*)xv)[i];
  float4 sc = *(const float4*)(scale + c);
  float4 sh = *(const float4*)(shift + c);
  float4 d = ((const float4*)dsta)[i];
  d.x += fmaxf(fmaf(sc.x, x.x, sh.x), 0.f);
  d.y += fmaxf(fmaf(sc.y, x.y, sh.y), 0.f);
  d.z += fmaxf(fmaf(sc.z, x.z, sh.z), 0.f);
  d.w += fmaxf(fmaf(sc.w, x.w, sh.w), 0.f);
  ((float4*)dsta)[i] = d;
}

// ---- column-sum partials of h ----
__global__ __launch_bounds__(256) void colsum_p(const float* __restrict__ h, float* __restrict__ hpart)
{
  __shared__ float red[8][32][4];
  int tid = threadIdx.x, tx = tid & 31, ty = tid >> 5;
  long rbase = (long)blockIdx.x * 80;
  float a0 = 0, a1 = 0, a2 = 0, a3 = 0;
  #pragma unroll
  for (int i = 0; i < 10; ++i) {
    long row = rbase + i * 8 + ty;
    float4 v = *(const float4*)(h + row * 128 + tx * 4);
    a0 += v.x; a1 += v.y; a2 += v.z; a3 += v.w;
  }
  red[ty][tx][0] = a0; red[ty][tx][1] = a1; red[ty][tx][2] = a2; red[ty][tx][3] = a3;
  __syncthreads();
  if (ty == 0) {
    float b0 = 0, b1 = 0, b2 = 0, b3 = 0;
    #pragma unroll
    for (int t = 0; t < 8; ++t) {
      b0 += red[t][tx][0]; b1 += red[t][tx][1]; b2 += red[t][tx][2]; b3 += red[t][tx][3];
    }
    float* bp = hpart + (long)blockIdx.x * 128;
    bp[tx * 4 + 0] = b0; bp[tx * 4 + 1] = b1; bp[tx * 4 + 2] = b2; bp[tx * 4 + 3] = b3;
  }
}

__global__ void cls_head(const float* __restrict__ hpart,
                         const float* __restrict__ W1, const float* __restrict__ b1,
                         const float* __restrict__ W2, const float* __restrict__ b2,
                         float* __restrict__ out)
{
  __shared__ float hm[128];
  __shared__ float r1[128];
  int t = threadIdx.x;
  float s = 0.f;
  for (int p = 0; p < 250; ++p) s += hpart[(long)p * 128 + t];
  hm[t] = s * (1.0f / NN);
  __syncthreads();
  float v = b1[t];
  for (int k = 0; k < 128; ++k) v = fmaf(hm[k], W1[k * 128 + t], v);
  r1[t] = fmaxf(v, 0.f);
  __syncthreads();
  if (t < 64) {
    float o = b2[t];
    for (int k = 0; k < 128; ++k) o = fmaf(r1[k], W2[k * 64 + t], o);
    out[t] = o;
  }
}

extern "C" void kernel_launch(void* const* d_in, const int* in_sizes, int n_in,
                              void* d_out, int out_size, void* d_ws, size_t ws_size,
                              hipStream_t stream)
{
  const float* h_in  = (const float*)d_in[0];
  const int*   ei    = (const int*)d_in[1];
  const float* eattr = (const float*)d_in[2];
  const float* nW    = (const float*)d_in[3];
  const float* nb    = (const float*)d_in[4];
  const float* eW    = (const float*)d_in[5];
  const float* eb    = (const float*)d_in[6];
  const float* LW    = (const float*)d_in[7];
  const float* LB    = (const float*)d_in[8];
  const float* G     = (const float*)d_in[9];
  const float* Bt    = (const float*)d_in[10];
  const float* W1    = (const float*)d_in[11];
  const float* b1    = (const float*)d_in[12];
  const float* W2    = (const float*)d_in[13];
  const float* b2    = (const float*)d_in[14];
  float* out = (float*)d_out;

  float* ws = (float*)d_ws;
  float* f_h     = ws;
  unsigned short* f_ehat = (unsigned short*)(f_h + (long)NN * 128);   // bf16, NE*128
  float* f_A     = (float*)(f_ehat + (long)NE * 128);
  float* f_B     = f_A    + (long)NN * 128;
  float* f_D     = f_B    + (long)NN * 128;
  float* f_E     = f_D    + (long)NN * 128;
  float* f_stats = f_E    + (long)NN * 128;
  float* f_npart = f_stats + S_TOTAL;
  float* f_epart = f_npart + 250 * 256;
  float* f_epart2= f_epart + (long)5000 * 256;
  float* f_hpart = f_epart2 + 50 * 256;
  unsigned short* e_bf = (unsigned short*)(f_hpart + 250 * 128);      // bf16, NE*128
  int* i_deg      = (int*)(e_bf + (long)NE * 128);
  int* i_rowstart = i_deg + NN;
  int* i_cursor   = i_rowstart + NN + 1;
  int* i_elist    = i_cursor + NN;
  int* i_srcp     = i_elist + NE;
  int* i_dstp     = i_srcp + NE;
  int* i_slot     = i_dstp + NE;
  size_t pw_off = ((((char*)(i_slot + NE)) - (char*)d_ws) + 15) & ~(size_t)15;
  unsigned short* pw_h = (unsigned short*)((char*)d_ws + pw_off);
  unsigned short* pw_l = pw_h + (long)17 * 16384;
  const int* src = ei;
  const int* dst = ei + NE;

  // ---- weight pre-split ----
  prep_w<<<64, 256, 0, stream>>>(nW, pw_h, pw_l, 1);
  prep_w<<<64, 256, 0, stream>>>(eW, pw_h + 16384, pw_l + 16384, 1);
  prep_w<<<960, 256, 0, stream>>>(LW, pw_h + 2 * 16384, pw_l + 2 * 16384, 15);

  // ---- CSR build + deterministic edge relabeling (slot space) ----
  hipMemsetAsync(i_deg, 0, NN * sizeof(int), stream);
  hist_dst<<<(NE + 255) / 256, 256, 0, stream>>>(dst, i_deg);
  scan_deg<<<1, 1024, 0, stream>>>(i_deg, i_rowstart, i_cursor);
  fill_csr<<<(NE + 255) / 256, 256, 0, stream>>>(dst, i_cursor, i_elist);
  seg_sort<<<NN, 128, 0, stream>>>(i_rowstart, i_elist);
  perm_edges<<<(NE + 255) / 256, 256, 0, stream>>>(i_elist, src, dst, i_srcp, i_dstp, i_slot);

  // ---- h embedding (fp32) ----
  gemm128<<<313, 256, 0, stream>>>(h_in, pw_h, pw_l, nb, f_h, NN);

  for (int l = 0; l < NL; ++l) {
    const unsigned short* lwh = pw_h + (long)(2 + l * 5) * 16384;
    const unsigned short* lwl = pw_l + (long)(2 + l * 5) * 16384;
    const float* bl = LB + (long)l * 5 * 128;
    int last = (l == NL - 1);

    gemm128_x4<<<dim3(313, 4), 256, 0, stream>>>(f_h, lwh, lwl, bl, f_A, f_B, f_D, f_E, NN);
    if (l == 0)
      edge_emb_fused0<<<5000, 256, 0, stream>>>(eattr, pw_h + 16384, pw_l + 16384, eb,
                                                lwh + 2 * 16384, lwl + 2 * 16384, bl + 2 * 128,
                                                src, dst, i_slot, f_D, f_E,
                                                e_bf, f_ehat, f_epart);
    else if (l == 1)
      edge_fusedU<true><<<5000, 256, 0, stream>>>(e_bf, f_ehat,
                                                  f_stats + S_ESC, f_stats + S_ESH,
                                                  lwh + 2 * 16384, lwl + 2 * 16384, bl + 2 * 128,
                                                  i_srcp, i_dstp, f_D, f_E, f_epart, 1);
    else
      edge_fusedU<false><<<5000, 256, 0, stream>>>(e_bf, f_ehat,
                                                   f_stats + S_ESC, f_stats + S_ESH,
                                                   lwh + 2 * 16384, lwl + 2 * 16384, bl + 2 * 128,
                                                   i_srcp, i_dstp, f_D, f_E, f_epart, 0);
    if (!last) {
      reduce_part<<<50, 256, 0, stream>>>(f_epart, f_epart2, 100);
      finalize_bn_p<<<1, 128, 0, stream>>>(f_epart2, 50, 1.0f / NE,
                                           G + (l * 2 + 1) * 128, Bt + (l * 2 + 1) * 128,
                                           f_stats + S_ESC, f_stats + S_ESH);
    }
    gather_node<<<NN, 128, 0, stream>>>(f_ehat, f_B, i_srcp, i_rowstart, f_A);
    stats128p<<<250, 256, 0, stream>>>(f_A, f_npart);
    finalize_bn_p<<<1, 128, 0, stream>>>(f_npart, 250, 1.0f / NN,
                                         G + (l * 2 + 0) * 128, Bt + (l * 2 + 0) * 128,
                                         f_stats + S_NSC, f_stats + S_NSH);
    pass2<<<2500, 256, 0, stream>>>(f_h, f_A, f_stats + S_NSC, f_stats + S_NSH, (long)NN * 32);
  }

  colsum_p<<<250, 256, 0, stream>>>(f_h, f_hpart);
  cls_head<<<1, 128, 0, stream>>>(f_hpart, W1, b1, W2, b2, out);
}

// Round 18
// 919.866 us; speedup vs baseline: 1.0563x; 1.0563x over previous
//
#include <hip/hip_runtime.h>
#include <math.h>

#define NN 20000
#define NE 320000
#define NL 3
#define EPSV 1e-5f
#define MAXD 128
#define ASZ 2560   // 64*40 shorts
#define WSZ 5120   // 128*40 shorts

// f_stats layout (floats)
#define S_ESC  0
#define S_ESH  128
#define S_NSC  256
#define S_NSH  384
#define S_TOTAL 512

typedef __attribute__((ext_vector_type(8))) short bf16x8;
typedef __attribute__((ext_vector_type(4))) float f32x4;

__device__ __forceinline__ float sigf(float x) { return 1.0f / (1.0f + expf(-x)); }
__device__ __forceinline__ float b2f(unsigned short s) { return __uint_as_float((unsigned)s << 16); }
__device__ __forceinline__ unsigned short f2b(float a)
{
  unsigned u = __float_as_uint(a);
  return (unsigned short)((u + 0x7FFFu + ((u >> 16) & 1u)) >> 16);
}

// round-to-nearest-even split: a ~= h + l (both bf16)
__device__ __forceinline__ void bsplit(float a, unsigned short& h, unsigned short& l)
{
  unsigned u = __float_as_uint(a);
  unsigned rh = (u + 0x7FFFu + ((u >> 16) & 1u)) >> 16;
  h = (unsigned short)rh;
  float hf = __uint_as_float(rh << 16);
  float d = a - hf;
  unsigned v = __float_as_uint(d);
  l = (unsigned short)((v + 0x7FFFu + ((v >> 16) & 1u)) >> 16);
}

// ---- weight pre-split: src fp32 [nmat][k][c] -> dh/dl bf16 [nmat][c][k] (k-transposed) ----
__global__ __launch_bounds__(256) void prep_w(const float* __restrict__ src,
                                              unsigned short* __restrict__ dh,
                                              unsigned short* __restrict__ dl, int nmat)
{
  int idx = blockIdx.x * 256 + threadIdx.x;
  if (idx >= nmat * 16384) return;
  int m = idx >> 14, r = idx & 16383, k = r >> 7, c = r & 127;
  unsigned short h, l;
  bsplit(src[idx], h, l);
  long o = ((long)m << 14) + c * 128 + k;
  dh[o] = h; dl[o] = l;
}

// ==== pipelined staging helpers ====
__device__ __forceinline__ void loadW(const unsigned short* __restrict__ Wh_g,
                                      const unsigned short* __restrict__ Wl_g,
                                      int k0, int tid, uint4& h0, uint4& h1, uint4& l0, uint4& l1)
{
  int c0 = tid >> 2, g = tid & 3, c1 = c0 + 64;
  h0 = *(const uint4*)(Wh_g + ((long)c0 << 7) + k0 + g * 8);
  h1 = *(const uint4*)(Wh_g + ((long)c1 << 7) + k0 + g * 8);
  l0 = *(const uint4*)(Wl_g + ((long)c0 << 7) + k0 + g * 8);
  l1 = *(const uint4*)(Wl_g + ((long)c1 << 7) + k0 + g * 8);
}
__device__ __forceinline__ void writeW(const uint4& h0, const uint4& h1, const uint4& l0,
                                       const uint4& l1, int tid,
                                       unsigned short* Wh, unsigned short* Wl)
{
  int c0 = tid >> 2, g = tid & 3, c1 = c0 + 64;
  *(uint4*)(Wh + c0 * 40 + g * 8) = h0;
  *(uint4*)(Wh + c1 * 40 + g * 8) = h1;
  *(uint4*)(Wl + c0 * 40 + g * 8) = l0;
  *(uint4*)(Wl + c1 * 40 + g * 8) = l1;
}
__device__ __forceinline__ void loadA_f32(const float* __restrict__ A, long base, int M,
                                          int tid, int k0, float4& a0, float4& a1)
{
  int r0 = tid >> 3, c4 = tid & 7;
  long g0 = base + r0, g1 = g0 + 32;
  a0 = (g0 < M) ? *(const float4*)(A + g0 * 128 + k0 + c4 * 4) : make_float4(0.f, 0.f, 0.f, 0.f);
  a1 = (g1 < M) ? *(const float4*)(A + g1 * 128 + k0 + c4 * 4) : make_float4(0.f, 0.f, 0.f, 0.f);
}
__device__ __forceinline__ void writeA_pair(const float4& a, int row, int c4,
                                            unsigned short* Ah, unsigned short* Al)
{
  unsigned short h0, l0, h1, l1, h2, l2, h3, l3;
  bsplit(a.x, h0, l0); bsplit(a.y, h1, l1); bsplit(a.z, h2, l2); bsplit(a.w, h3, l3);
  *(uint2*)(Ah + row * 40 + c4 * 4) =
      make_uint2((unsigned)h0 | ((unsigned)h1 << 16), (unsigned)h2 | ((unsigned)h3 << 16));
  *(uint2*)(Al + row * 40 + c4 * 4) =
      make_uint2((unsigned)l0 | ((unsigned)l1 << 16), (unsigned)l2 | ((unsigned)l3 << 16));
}
__device__ __forceinline__ void writeA_bf(const float4& a, int row, int c4, unsigned short* Ah)
{
  *(uint2*)(Ah + row * 40 + c4 * 4) = make_uint2(
      (unsigned)f2b(a.x) | ((unsigned)f2b(a.y) << 16),
      (unsigned)f2b(a.z) | ((unsigned)f2b(a.w) << 16));
}

// ---- MFMA fragment compute: split A (3 MFMAs), W from LDS ----
__device__ __forceinline__ void mfma_frags(int lane, int w, f32x4 acc[4][2],
    const unsigned short* Ah, const unsigned short* Al,
    const unsigned short* Wh, const unsigned short* Wl)
{
  int r16 = lane & 15, g8 = lane >> 4;
  bf16x8 ah[4], al[4], wh[2], wl[2];
  #pragma unroll
  for (int rg = 0; rg < 4; ++rg) {
    ah[rg] = *(const bf16x8*)(Ah + (rg * 16 + r16) * 40 + g8 * 8);
    al[rg] = *(const bf16x8*)(Al + (rg * 16 + r16) * 40 + g8 * 8);
  }
  #pragma unroll
  for (int cg = 0; cg < 2; ++cg) {
    int c = w * 32 + cg * 16 + r16;
    wh[cg] = *(const bf16x8*)(Wh + c * 40 + g8 * 8);
    wl[cg] = *(const bf16x8*)(Wl + c * 40 + g8 * 8);
  }
  #pragma unroll
  for (int rg = 0; rg < 4; ++rg)
    #pragma unroll
    for (int cg = 0; cg < 2; ++cg) {
      acc[rg][cg] = __builtin_amdgcn_mfma_f32_16x16x32_bf16(ah[rg], wh[cg], acc[rg][cg], 0, 0, 0);
      acc[rg][cg] = __builtin_amdgcn_mfma_f32_16x16x32_bf16(ah[rg], wl[cg], acc[rg][cg], 0, 0, 0);
      acc[rg][cg] = __builtin_amdgcn_mfma_f32_16x16x32_bf16(al[rg], wh[cg], acc[rg][cg], 0, 0, 0);
    }
}

// ---- MFMA fragment compute: single-bf16 A (2 MFMAs), W from LDS ----
__device__ __forceinline__ void mfma_frags2(int lane, int w, f32x4 acc[4][2],
    const unsigned short* Ah, const unsigned short* Wh, const unsigned short* Wl)
{
  int r16 = lane & 15, g8 = lane >> 4;
  bf16x8 ah[4], wh[2], wl[2];
  #pragma unroll
  for (int rg = 0; rg < 4; ++rg)
    ah[rg] = *(const bf16x8*)(Ah + (rg * 16 + r16) * 40 + g8 * 8);
  #pragma unroll
  for (int cg = 0; cg < 2; ++cg) {
    int c = w * 32 + cg * 16 + r16;
    wh[cg] = *(const bf16x8*)(Wh + c * 40 + g8 * 8);
    wl[cg] = *(const bf16x8*)(Wl + c * 40 + g8 * 8);
  }
  #pragma unroll
  for (int rg = 0; rg < 4; ++rg)
    #pragma unroll
    for (int cg = 0; cg < 2; ++cg) {
      acc[rg][cg] = __builtin_amdgcn_mfma_f32_16x16x32_bf16(ah[rg], wh[cg], acc[rg][cg], 0, 0, 0);
      acc[rg][cg] = __builtin_amdgcn_mfma_f32_16x16x32_bf16(ah[rg], wl[cg], acc[rg][cg], 0, 0, 0);
    }
}

#define ACC_INIT                          \
  _Pragma("unroll")                       \
  for (int rg = 0; rg < 4; ++rg)          \
    _Pragma("unroll")                     \
    for (int cg = 0; cg < 2; ++cg)        \
      acc[rg][cg] = (f32x4){0.f, 0.f, 0.f, 0.f};

// ---- core, fp32 input (bsplit on the fly); dbuf LDS; split A ----
__device__ __forceinline__ void mfma_core_f32(
    const float* __restrict__ A, long base, int M,
    const unsigned short* __restrict__ Wh_g, const unsigned short* __restrict__ Wl_g,
    int tid, f32x4 acc[4][2],
    unsigned short* Ah, unsigned short* Al, unsigned short* Wh, unsigned short* Wl)
{
  int lane = tid & 63, w = tid >> 6;
  int r0 = tid >> 3, c4 = tid & 7;
  ACC_INIT
  float4 a0, a1; uint4 h0, h1, l0, l1;
  loadA_f32(A, base, M, tid, 0, a0, a1);
  loadW(Wh_g, Wl_g, 0, tid, h0, h1, l0, l1);
  writeA_pair(a0, r0, c4, Ah, Al);
  writeA_pair(a1, r0 + 32, c4, Ah, Al);
  writeW(h0, h1, l0, l1, tid, Wh, Wl);
  for (int ks = 0; ks < 4; ++ks) {
    __syncthreads();
    int cb = ks & 1, nb = cb ^ 1;
    if (ks < 3) {
      loadA_f32(A, base, M, tid, 32 * (ks + 1), a0, a1);
      loadW(Wh_g, Wl_g, 32 * (ks + 1), tid, h0, h1, l0, l1);
    }
    mfma_frags(lane, w, acc, Ah + cb * ASZ, Al + cb * ASZ, Wh + cb * WSZ, Wl + cb * WSZ);
    if (ks < 3) {
      writeA_pair(a0, r0, c4, Ah + nb * ASZ, Al + nb * ASZ);
      writeA_pair(a1, r0 + 32, c4, Ah + nb * ASZ, Al + nb * ASZ);
      writeW(h0, h1, l0, l1, tid, Wh + nb * WSZ, Wl + nb * WSZ);
    }
  }
}

// ---- core, fp32 rows via ridx -> bf16-A staging (2 MFMA); dbuf LDS ----
__device__ __forceinline__ void mfma_core_bf16i(
    const float* __restrict__ A, const int* ridx,
    const unsigned short* __restrict__ Wh_g, const unsigned short* __restrict__ Wl_g,
    int tid, f32x4 acc[4][2],
    unsigned short* Ah, unsigned short* Wh, unsigned short* Wl)
{
  int lane = tid & 63, w = tid >> 6;
  int r0 = tid >> 3, c4 = tid & 7;
  long g0 = ridx[r0], g1 = ridx[r0 + 32];
  ACC_INIT
  float4 a0, a1; uint4 h0, h1, l0, l1;
  a0 = *(const float4*)(A + g0 * 128 + c4 * 4);
  a1 = *(const float4*)(A + g1 * 128 + c4 * 4);
  loadW(Wh_g, Wl_g, 0, tid, h0, h1, l0, l1);
  writeA_bf(a0, r0, c4, Ah);
  writeA_bf(a1, r0 + 32, c4, Ah);
  writeW(h0, h1, l0, l1, tid, Wh, Wl);
  for (int ks = 0; ks < 4; ++ks) {
    __syncthreads();
    int cb = ks & 1, nb = cb ^ 1;
    if (ks < 3) {
      int k0 = 32 * (ks + 1);
      a0 = *(const float4*)(A + g0 * 128 + k0 + c4 * 4);
      a1 = *(const float4*)(A + g1 * 128 + k0 + c4 * 4);
      loadW(Wh_g, Wl_g, k0, tid, h0, h1, l0, l1);
    }
    mfma_frags2(lane, w, acc, Ah + cb * ASZ, Wh + cb * WSZ, Wl + cb * WSZ);
    if (ks < 3) {
      writeA_bf(a0, r0, c4, Ah + nb * ASZ);
      writeA_bf(a1, r0 + 32, c4, Ah + nb * ASZ);
      writeW(h0, h1, l0, l1, tid, Wh + nb * WSZ, Wl + nb * WSZ);
    }
  }
}

// ---- core, single-bf16 A input (e plane); 2-MFMA frags ----
__device__ __forceinline__ void mfma_core_bf16(
    const unsigned short* __restrict__ Abf, long base,
    const unsigned short* __restrict__ Wh_g, const unsigned short* __restrict__ Wl_g,
    int tid, f32x4 acc[4][2],
    unsigned short* Ah, unsigned short* Wh, unsigned short* Wl)
{
  int lane = tid & 63, w = tid >> 6;
  int row = tid >> 2, q = tid & 3;
  ACC_INIT
  uint4 av, h0, h1, l0, l1;
  long gof = (base + row) * 128 + q * 8;
  av = *(const uint4*)(Abf + gof);
  loadW(Wh_g, Wl_g, 0, tid, h0, h1, l0, l1);
  *(uint4*)(Ah + row * 40 + q * 8) = av;
  writeW(h0, h1, l0, l1, tid, Wh, Wl);
  for (int ks = 0; ks < 4; ++ks) {
    __syncthreads();
    int cb = ks & 1, nb = cb ^ 1;
    if (ks < 3) {
      int k0 = 32 * (ks + 1);
      av = *(const uint4*)(Abf + gof + k0);
      loadW(Wh_g, Wl_g, k0, tid, h0, h1, l0, l1);
    }
    mfma_frags2(lane, w, acc, Ah + cb * ASZ, Wh + cb * WSZ, Wl + cb * WSZ);
    if (ks < 3) {
      *(uint4*)(Ah + nb * ASZ + row * 40 + q * 8) = av;
      writeW(h0, h1, l0, l1, tid, Wh + nb * WSZ, Wl + nb * WSZ);
    }
  }
}

// ---- core, fused edge update: e_new = e + relu(sc*ehat + sh); e,ehat bf16 ----
template<bool WB>
__device__ __forceinline__ void mfma_core_upd(
    unsigned short* __restrict__ Ebf,
    const unsigned short* __restrict__ EHAT, long base,
    const unsigned short* __restrict__ Wh_g, const unsigned short* __restrict__ Wl_g,
    const float* s_sc, const float* s_sh,
    int tid, f32x4 acc[4][2],
    unsigned short* Ah, unsigned short* Wh, unsigned short* Wl)
{
  int lane = tid & 63, w = tid >> 6;
  int row = tid >> 2, q = tid & 3;
  ACC_INIT
  uint4 ev, hv, h0, h1, l0, l1;
  long grow = (base + row) * 128;

  ev = *(const uint4*)(Ebf + grow + q * 8);
  hv = *(const uint4*)(EHAT + grow + q * 8);
  loadW(Wh_g, Wl_g, 0, tid, h0, h1, l0, l1);

  #pragma unroll 1
  for (int ks = 0; ks < 4; ++ks) {
    int cb = ks & 1;
    int cbase = ks * 32 + q * 8;
    {
      unsigned es[8] = {ev.x & 0xFFFFu, ev.x >> 16, ev.y & 0xFFFFu, ev.y >> 16,
                        ev.z & 0xFFFFu, ev.z >> 16, ev.w & 0xFFFFu, ev.w >> 16};
      unsigned hs[8] = {hv.x & 0xFFFFu, hv.x >> 16, hv.y & 0xFFFFu, hv.y >> 16,
                        hv.z & 0xFFFFu, hv.z >> 16, hv.w & 0xFFFFu, hv.w >> 16};
      unsigned short nv[8];
      #pragma unroll
      for (int i = 0; i < 8; ++i) {
        float v = b2f((unsigned short)es[i]) +
                  fmaxf(fmaf(s_sc[cbase + i], b2f((unsigned short)hs[i]), s_sh[cbase + i]), 0.f);
        nv[i] = f2b(v);
      }
      uint4 nq = make_uint4((unsigned)nv[0] | ((unsigned)nv[1] << 16),
                            (unsigned)nv[2] | ((unsigned)nv[3] << 16),
                            (unsigned)nv[4] | ((unsigned)nv[5] << 16),
                            (unsigned)nv[6] | ((unsigned)nv[7] << 16));
      *(uint4*)(Ah + cb * ASZ + row * 40 + q * 8) = nq;
      if (WB) *(uint4*)(Ebf + grow + cbase) = nq;
      writeW(h0, h1, l0, l1, tid, Wh + cb * WSZ, Wl + cb * WSZ);
    }
    __syncthreads();
    if (ks < 3) {
      int k0 = 32 * (ks + 1);
      ev = *(const uint4*)(Ebf + grow + k0 + q * 8);
      hv = *(const uint4*)(EHAT + grow + k0 + q * 8);
      loadW(Wh_g, Wl_g, k0, tid, h0, h1, l0, l1);
    }
    mfma_frags2(lane, w, acc, Ah + cb * ASZ, Wh + cb * WSZ, Wl + cb * WSZ);
    if (ks < 2) __syncthreads();
  }
}

// ---- shared edge epilogue: e_hat = Ce+b+Dh[dst]+Eh[src]; store bf16 + BN partials ----
// Dh/Eh are bf16 rows.
__device__ __forceinline__ void edge_epilogue(
    f32x4 acc[4][2], const float* __restrict__ bias,
    const int* __restrict__ srcp, const int* __restrict__ dstp,
    const unsigned short* __restrict__ Dh, const unsigned short* __restrict__ Eh,
    unsigned short* __restrict__ ehat, float* __restrict__ epart, int do_stats,
    long base, int tid)
{
  int lane = tid & 63, w = tid >> 6;
  int r16 = lane & 15, g8 = lane >> 4;
  int colA = w * 32 + r16, colB = colA + 16;
  float bA = bias[colA], bB = bias[colB];
  float s0 = 0.f, s1 = 0.f, q0 = 0.f, q1 = 0.f;
  #pragma unroll
  for (int rg = 0; rg < 4; ++rg)
    #pragma unroll
    for (int j = 0; j < 4; ++j) {
      long erow = base + rg * 16 + g8 * 4 + j;  // NE multiple of 64
      int si = srcp[erow], di = dstp[erow];
      const unsigned short* dhp = Dh + (long)di * 128;
      const unsigned short* ehp = Eh + (long)si * 128;
      float xA = acc[rg][0][j] + bA + b2f(dhp[colA]) + b2f(ehp[colA]);
      float xB = acc[rg][1][j] + bB + b2f(dhp[colB]) + b2f(ehp[colB]);
      ehat[erow * 128 + colA] = f2b(xA);
      ehat[erow * 128 + colB] = f2b(xB);
      s0 += xA; q0 += xA * xA; s1 += xB; q1 += xB * xB;
    }
  if (do_stats) {
    s0 += __shfl_xor(s0, 16); s0 += __shfl_xor(s0, 32);
    q0 += __shfl_xor(q0, 16); q0 += __shfl_xor(q0, 32);
    s1 += __shfl_xor(s1, 16); s1 += __shfl_xor(s1, 32);
    q1 += __shfl_xor(q1, 16); q1 += __shfl_xor(q1, 32);
    if (g8 == 0) {
      float* bp = epart + (long)blockIdx.x * 256;
      bp[colA] = s0;       bp[128 + colA] = q0;
      bp[colB] = s1;       bp[128 + colB] = q1;
    }
  }
}

// ---- C[M,128] = A @ W + b (fp32 out; h embedding) ----
__global__ __launch_bounds__(256) void gemm128(
    const float* __restrict__ A, const unsigned short* __restrict__ Wh_g,
    const unsigned short* __restrict__ Wl_g, const float* __restrict__ bias,
    float* __restrict__ C, int M)
{
  __shared__ unsigned short Ah[2 * ASZ], Al[2 * ASZ], Wh[2 * WSZ], Wl[2 * WSZ];
  int tid = threadIdx.x, lane = tid & 63, w = tid >> 6;
  int r16 = lane & 15, g8 = lane >> 4;
  long base = (long)blockIdx.x * 64;
  f32x4 acc[4][2];
  mfma_core_f32(A, base, M, Wh_g, Wl_g, tid, acc, Ah, Al, Wh, Wl);
  #pragma unroll
  for (int cg = 0; cg < 2; ++cg) {
    int col = w * 32 + cg * 16 + r16;
    float b = bias[col];
    #pragma unroll
    for (int rg = 0; rg < 4; ++rg)
      #pragma unroll
      for (int j = 0; j < 4; ++j) {
        long row = base + rg * 16 + g8 * 4 + j;
        if (row < M) C[row * 128 + col] = acc[rg][cg][j] + b;
      }
  }
}

// ---- e embedding: rows via elist; bf16-A staging; bf16 out (slot space) ----
__global__ __launch_bounds__(256) void gemm128s(
    const float* __restrict__ A, const int* __restrict__ rows,
    const unsigned short* __restrict__ Wh_g, const unsigned short* __restrict__ Wl_g,
    const float* __restrict__ bias,
    unsigned short* __restrict__ Cbf)
{
  __shared__ unsigned short Ah[2 * ASZ], Wh[2 * WSZ], Wl[2 * WSZ];
  __shared__ int ridx[64];
  int tid = threadIdx.x, lane = tid & 63, w = tid >> 6;
  int r16 = lane & 15, g8 = lane >> 4;
  long base = (long)blockIdx.x * 64;
  if (tid < 64) ridx[tid] = rows[base + tid];
  __syncthreads();
  f32x4 acc[4][2];
  mfma_core_bf16i(A, ridx, Wh_g, Wl_g, tid, acc, Ah, Wh, Wl);
  #pragma unroll
  for (int cg = 0; cg < 2; ++cg) {
    int col = w * 32 + cg * 16 + r16;
    float b = bias[col];
    #pragma unroll
    for (int rg = 0; rg < 4; ++rg)
      #pragma unroll
      for (int j = 0; j < 4; ++j) {
        long row = base + rg * 16 + g8 * 4 + j;
        Cbf[row * 128 + col] = f2b(acc[rg][cg][j] + b);
      }
  }
}

// ---- 4 node GEMMs (A,B,D,E): A fp32 out, B/D/E bf16 out ----
__global__ __launch_bounds__(256) void gemm128_x4(
    const float* __restrict__ A, const unsigned short* __restrict__ Wh_l,
    const unsigned short* __restrict__ Wl_l, const float* __restrict__ bl,
    float* __restrict__ o0, unsigned short* __restrict__ o1,
    unsigned short* __restrict__ o2, unsigned short* __restrict__ o3, int M)
{
  __shared__ unsigned short Ah[2 * ASZ], Al[2 * ASZ], Wh[2 * WSZ], Wl[2 * WSZ];
  int y = blockIdx.y;
  int widx = (y < 2) ? y : y + 1;  // {0,1,3,4}
  const unsigned short* Wh_g = Wh_l + ((long)widx << 14);
  const unsigned short* Wl_g = Wl_l + ((long)widx << 14);
  const float* bias = bl + (long)widx * 128;
  int tid = threadIdx.x, lane = tid & 63, w = tid >> 6;
  int r16 = lane & 15, g8 = lane >> 4;
  long base = (long)blockIdx.x * 64;
  f32x4 acc[4][2];
  mfma_core_f32(A, base, M, Wh_g, Wl_g, tid, acc, Ah, Al, Wh, Wl);
  if (y == 0) {
    #pragma unroll
    for (int cg = 0; cg < 2; ++cg) {
      int col = w * 32 + cg * 16 + r16;
      float b = bias[col];
      #pragma unroll
      for (int rg = 0; rg < 4; ++rg)
        #pragma unroll
        for (int j = 0; j < 4; ++j) {
          long row = base + rg * 16 + g8 * 4 + j;
          if (row < M) o0[row * 128 + col] = acc[rg][cg][j] + b;
        }
    }
  } else {
    unsigned short* C = (y == 1) ? o1 : (y == 2) ? o2 : o3;
    #pragma unroll
    for (int cg = 0; cg < 2; ++cg) {
      int col = w * 32 + cg * 16 + r16;
      float b = bias[col];
      #pragma unroll
      for (int rg = 0; rg < 4; ++rg)
        #pragma unroll
        for (int j = 0; j < 4; ++j) {
          long row = base + rg * 16 + g8 * 4 + j;
          if (row < M) C[row * 128 + col] = f2b(acc[rg][cg][j] + b);
        }
    }
  }
}

// ---- edge_fused layer 0: bf16-e GEMM + epilogue ----
__global__ __launch_bounds__(256) void edge_fused0(
    const unsigned short* __restrict__ ebf,
    const unsigned short* __restrict__ Wh_g, const unsigned short* __restrict__ Wl_g,
    const float* __restrict__ bias, const int* __restrict__ srcp, const int* __restrict__ dstp,
    const unsigned short* __restrict__ Dh, const unsigned short* __restrict__ Eh,
    unsigned short* __restrict__ ehat, float* __restrict__ epart, int do_stats)
{
  __shared__ unsigned short Ah[2 * ASZ], Wh[2 * WSZ], Wl[2 * WSZ];
  int tid = threadIdx.x;
  long base = (long)blockIdx.x * 64;
  f32x4 acc[4][2];
  mfma_core_bf16(ebf, base, Wh_g, Wl_g, tid, acc, Ah, Wh, Wl);
  edge_epilogue(acc, bias, srcp, dstp, Dh, Eh, ehat, epart, do_stats, base, tid);
}

// ---- edge_fused layers 1,2: fused e-update staging + GEMM + epilogue ----
template<bool WB>
__global__ __launch_bounds__(256) void edge_fusedU(
    unsigned short* __restrict__ ebf,
    unsigned short* __restrict__ ehat,
    const float* __restrict__ scale, const float* __restrict__ shift,
    const unsigned short* __restrict__ Wh_g, const unsigned short* __restrict__ Wl_g,
    const float* __restrict__ bias, const int* __restrict__ srcp, const int* __restrict__ dstp,
    const unsigned short* __restrict__ Dh, const unsigned short* __restrict__ Eh,
    float* __restrict__ epart, int do_stats)
{
  __shared__ unsigned short Ah[2 * ASZ], Wh[2 * WSZ], Wl[2 * WSZ];
  __shared__ float s_sc[128], s_sh[128];
  int tid = threadIdx.x;
  if (tid < 128) { s_sc[tid] = scale[tid]; s_sh[tid] = shift[tid]; }
  __syncthreads();
  long base = (long)blockIdx.x * 64;
  f32x4 acc[4][2];
  mfma_core_upd<WB>(ebf, ehat, base, Wh_g, Wl_g, s_sc, s_sh, tid, acc, Ah, Wh, Wl);
  edge_epilogue(acc, bias, srcp, dstp, Dh, Eh, ehat, epart, do_stats, base, tid);
}

// ---- generic partial reduce ----
__global__ __launch_bounds__(256) void reduce_part(const float* __restrict__ in,
                                                   float* __restrict__ outp, int groups)
{
  int t = threadIdx.x;
  long base = (long)blockIdx.x * groups * 256;
  float acc = 0.f;
  for (int i = 0; i < groups; ++i) acc += in[base + i * 256 + t];
  outp[(long)blockIdx.x * 256 + t] = acc;
}

__global__ void finalize_bn_p(const float* __restrict__ part, int np, float invn,
                              const float* __restrict__ gamma, const float* __restrict__ beta,
                              float* __restrict__ scale, float* __restrict__ shift)
{
  int c = threadIdx.x;  // 128
  float s = 0.f, q = 0.f;
  for (int p = 0; p < np; ++p) {
    s += part[(long)p * 256 + c];
    q += part[(long)p * 256 + 128 + c];
  }
  float mu = s * invn;
  float var = q * invn - mu * mu;
  float sc = gamma[c] * rsqrtf(var + EPSV);
  scale[c] = sc;
  shift[c] = beta[c] - sc * mu;
}

// ==================== CSR build (by dst) ====================
__global__ __launch_bounds__(256) void hist_dst(const int* __restrict__ dst, int* __restrict__ deg)
{
  int e = blockIdx.x * 256 + threadIdx.x;
  if (e < NE) atomicAdd(&deg[dst[e]], 1);
}

__global__ __launch_bounds__(1024) void scan_deg(const int* __restrict__ deg,
                                                 int* __restrict__ rowstart, int* __restrict__ cursor)
{
  __shared__ int wsum[16];
  __shared__ int carry;
  int tid = threadIdx.x, lane = tid & 63, wid = tid >> 6;
  if (tid == 0) carry = 0;
  __syncthreads();
  for (int base = 0; base < NN; base += 1024) {
    int i = base + tid;
    int v = (i < NN) ? deg[i] : 0;
    int x = v;
    #pragma unroll
    for (int off = 1; off < 64; off <<= 1) {
      int y = __shfl_up(x, off, 64);
      if (lane >= off) x += y;
    }
    if (lane == 63) wsum[wid] = x;
    __syncthreads();
    int wpref = 0;
    for (int j = 0; j < wid; ++j) wpref += wsum[j];
    int excl = carry + wpref + x - v;
    if (i < NN) { rowstart[i] = excl; cursor[i] = excl; }
    __syncthreads();
    if (tid == 1023) carry = excl + v;
    __syncthreads();
  }
  if (tid == 0) rowstart[NN] = NE;
}

__global__ __launch_bounds__(256) void fill_csr(const int* __restrict__ dst,
                                                int* __restrict__ cursor, int* __restrict__ elist)
{
  int e = blockIdx.x * 256 + threadIdx.x;
  if (e < NE) {
    int p = atomicAdd(&cursor[dst[e]], 1);
    elist[p] = e;
  }
}

// ---- deterministic order: sort each node's segment by edge id ----
__global__ __launch_bounds__(128) void seg_sort(const int* __restrict__ rowstart,
                                                int* __restrict__ elist)
{
  __shared__ int buf[MAXD];
  __shared__ int srt[MAXD];
  int n = blockIdx.x;
  int s = rowstart[n], t = rowstart[n + 1];
  int deg = t - s;
  if (deg > MAXD) deg = MAXD;
  int tid = threadIdx.x;
  if (tid < deg) buf[tid] = elist[s + tid];
  __syncthreads();
  if (tid < deg) {
    int v = buf[tid], r = 0;
    for (int j = 0; j < deg; ++j) r += (buf[j] < v);
    srt[r] = v;
  }
  __syncthreads();
  if (tid < deg) elist[s + tid] = srt[tid];
}

// ---- permuted src/dst arrays (slot space) ----
__global__ __launch_bounds__(256) void perm_edges(const int* __restrict__ elist,
                                                  const int* __restrict__ src,
                                                  const int* __restrict__ dst,
                                                  int* __restrict__ srcp, int* __restrict__ dstp)
{
  int s = blockIdx.x * 256 + threadIdx.x;
  if (s < NE) {
    int e = elist[s];
    srcp[s] = src[e];
    dstp[s] = dst[e];
  }
}

// ---- per-node gather, CSR-contiguous; ehat and Bh are bf16 ----
__global__ __launch_bounds__(128) void gather_node(
    const unsigned short* __restrict__ ehat, const unsigned short* __restrict__ Bh,
    const int* __restrict__ srcp, const int* __restrict__ rowstart, float* __restrict__ x)
{
  __shared__ int ssrc[MAXD];
  int n = blockIdx.x;
  int s = rowstart[n], t = rowstart[n + 1];
  int deg = t - s;
  int nload = deg < MAXD ? deg : MAXD;
  int tid = threadIdx.x;
  if (tid < nload) ssrc[tid] = srcp[s + tid];
  __syncthreads();
  float acc = 0.f;
  for (int k = 0; k < nload; ++k)
    acc += sigf(b2f(ehat[(long)(s + k) * 128 + tid])) * b2f(Bh[(long)ssrc[k] * 128 + tid]);
  for (int k = MAXD; k < deg; ++k)
    acc += sigf(b2f(ehat[(long)(s + k) * 128 + tid])) * b2f(Bh[(long)srcp[s + k] * 128 + tid]);
  x[(long)n * 128 + tid] += acc;
}

// ---- node BN partials: 250 blocks x 80 rows ----
__global__ __launch_bounds__(256) void stats128p(const float* __restrict__ x, float* __restrict__ part)
{
  __shared__ float red[8][32][8];
  int tid = threadIdx.x, tx = tid & 31, ty = tid >> 5;
  long rbase = (long)blockIdx.x * 80;
  float a0 = 0, a1 = 0, a2 = 0, a3 = 0, c0 = 0, c1 = 0, c2 = 0, c3 = 0;
  #pragma unroll
  for (int i = 0; i < 10; ++i) {
    long row = rbase + i * 8 + ty;
    float4 v = *(const float4*)(x + row * 128 + tx * 4);
    a0 += v.x; a1 += v.y; a2 += v.z; a3 += v.w;
    c0 += v.x * v.x; c1 += v.y * v.y; c2 += v.z * v.z; c3 += v.w * v.w;
  }
  red[ty][tx][0] = a0; red[ty][tx][1] = a1; red[ty][tx][2] = a2; red[ty][tx][3] = a3;
  red[ty][tx][4] = c0; red[ty][tx][5] = c1; red[ty][tx][6] = c2; red[ty][tx][7] = c3;
  __syncthreads();
  if (ty == 0) {
    float b0 = 0, b1 = 0, b2 = 0, b3 = 0, d0 = 0, d1 = 0, d2 = 0, d3 = 0;
    #pragma unroll
    for (int t = 0; t < 8; ++t) {
      b0 += red[t][tx][0]; b1 += red[t][tx][1]; b2 += red[t][tx][2]; b3 += red[t][tx][3];
      d0 += red[t][tx][4]; d1 += red[t][tx][5]; d2 += red[t][tx][6]; d3 += red[t][tx][7];
    }
    float* bp = part + (long)blockIdx.x * 256;
    bp[tx * 4 + 0] = b0; bp[tx * 4 + 1] = b1; bp[tx * 4 + 2] = b2; bp[tx * 4 + 3] = b3;
    bp[128 + tx * 4 + 0] = d0; bp[128 + tx * 4 + 1] = d1;
    bp[128 + tx * 4 + 2] = d2; bp[128 + tx * 4 + 3] = d3;
  }
}

// ---- node pass 2: h += relu(bn(x)) ----
__global__ __launch_bounds__(256) void pass2(
    float* __restrict__ dsta, const float* __restrict__ xv,
    const float* __restrict__ scale, const float* __restrict__ shift, long n4)
{
  long i = (long)blockIdx.x * 256 + threadIdx.x;
  if (i >= n4) return;
  int c = (int)(i & 31) * 4;
  float4 x = ((const float4*)xv)[i];
  float4 sc = *(const float4*)(scale + c);
  float4 sh = *(const float4*)(shift + c);
  float4 d = ((const float4*)dsta)[i];
  d.x += fmaxf(fmaf(sc.x, x.x, sh.x), 0.f);
  d.y += fmaxf(fmaf(sc.y, x.y, sh.y), 0.f);
  d.z += fmaxf(fmaf(sc.z, x.z, sh.z), 0.f);
  d.w += fmaxf(fmaf(sc.w, x.w, sh.w), 0.f);
  ((float4*)dsta)[i] = d;
}

// ---- column-sum partials of h ----
__global__ __launch_bounds__(256) void colsum_p(const float* __restrict__ h, float* __restrict__ hpart)
{
  __shared__ float red[8][32][4];
  int tid = threadIdx.x, tx = tid & 31, ty = tid >> 5;
  long rbase = (long)blockIdx.x * 80;
  float a0 = 0, a1 = 0, a2 = 0, a3 = 0;
  #pragma unroll
  for (int i = 0; i < 10; ++i) {
    long row = rbase + i * 8 + ty;
    float4 v = *(const float4*)(h + row * 128 + tx * 4);
    a0 += v.x; a1 += v.y; a2 += v.z; a3 += v.w;
  }
  red[ty][tx][0] = a0; red[ty][tx][1] = a1; red[ty][tx][2] = a2; red[ty][tx][3] = a3;
  __syncthreads();
  if (ty == 0) {
    float b0 = 0, b1 = 0, b2 = 0, b3 = 0;
    #pragma unroll
    for (int t = 0; t < 8; ++t) {
      b0 += red[t][tx][0]; b1 += red[t][tx][1]; b2 += red[t][tx][2]; b3 += red[t][tx][3];
    }
    float* bp = hpart + (long)blockIdx.x * 128;
    bp[tx * 4 + 0] = b0; bp[tx * 4 + 1] = b1; bp[tx * 4 + 2] = b2; bp[tx * 4 + 3] = b3;
  }
}

__global__ void cls_head(const float* __restrict__ hpart,
                         const float* __restrict__ W1, const float* __restrict__ b1,
                         const float* __restrict__ W2, const float* __restrict__ b2,
                         float* __restrict__ out)
{
  __shared__ float hm[128];
  __shared__ float r1[128];
  int t = threadIdx.x;
  float s = 0.f;
  for (int p = 0; p < 250; ++p) s += hpart[(long)p * 128 + t];
  hm[t] = s * (1.0f / NN);
  __syncthreads();
  float v = b1[t];
  for (int k = 0; k < 128; ++k) v = fmaf(hm[k], W1[k * 128 + t], v);
  r1[t] = fmaxf(v, 0.f);
  __syncthreads();
  if (t < 64) {
    float o = b2[t];
    for (int k = 0; k < 128; ++k) o = fmaf(r1[k], W2[k * 64 + t], o);
    out[t] = o;
  }
}

extern "C" void kernel_launch(void* const* d_in, const int* in_sizes, int n_in,
                              void* d_out, int out_size, void* d_ws, size_t ws_size,
                              hipStream_t stream)
{
  const float* h_in  = (const float*)d_in[0];
  const int*   ei    = (const int*)d_in[1];
  const float* eattr = (const float*)d_in[2];
  const float* nW    = (const float*)d_in[3];
  const float* nb    = (const float*)d_in[4];
  const float* eW    = (const float*)d_in[5];
  const float* eb    = (const float*)d_in[6];
  const float* LW    = (const float*)d_in[7];
  const float* LB    = (const float*)d_in[8];
  const float* G     = (const float*)d_in[9];
  const float* Bt    = (const float*)d_in[10];
  const float* W1    = (const float*)d_in[11];
  const float* b1    = (const float*)d_in[12];
  const float* W2    = (const float*)d_in[13];
  const float* b2    = (const float*)d_in[14];
  float* out = (float*)d_out;

  float* ws = (float*)d_ws;
  float* f_h     = ws;
  unsigned short* f_ehat = (unsigned short*)(f_h + (long)NN * 128);   // bf16, NE*128
  float* f_A     = (float*)(f_ehat + (long)NE * 128);
  unsigned short* b_B = (unsigned short*)(f_A + (long)NN * 128);      // bf16 NN*128
  unsigned short* b_D = b_B + (long)NN * 128;
  unsigned short* b_E = b_D + (long)NN * 128;
  float* f_stats = (float*)(b_E + (long)NN * 128);
  float* f_npart = f_stats + S_TOTAL;
  float* f_epart = f_npart + 250 * 256;
  float* f_epart2= f_epart + (long)5000 * 256;
  float* f_hpart = f_epart2 + 50 * 256;
  unsigned short* e_bf = (unsigned short*)(f_hpart + 250 * 128);      // bf16, NE*128
  int* i_deg      = (int*)(e_bf + (long)NE * 128);
  int* i_rowstart = i_deg + NN;
  int* i_cursor   = i_rowstart + NN + 1;
  int* i_elist    = i_cursor + NN;
  int* i_srcp     = i_elist + NE;
  int* i_dstp     = i_srcp + NE;
  size_t pw_off = ((((char*)(i_dstp + NE)) - (char*)d_ws) + 15) & ~(size_t)15;
  unsigned short* pw_h = (unsigned short*)((char*)d_ws + pw_off);
  unsigned short* pw_l = pw_h + (long)17 * 16384;
  const int* src = ei;
  const int* dst = ei + NE;

  // ---- weight pre-split ----
  prep_w<<<64, 256, 0, stream>>>(nW, pw_h, pw_l, 1);
  prep_w<<<64, 256, 0, stream>>>(eW, pw_h + 16384, pw_l + 16384, 1);
  prep_w<<<960, 256, 0, stream>>>(LW, pw_h + 2 * 16384, pw_l + 2 * 16384, 15);

  // ---- CSR build + deterministic edge relabeling (slot space) ----
  hipMemsetAsync(i_deg, 0, NN * sizeof(int), stream);
  hist_dst<<<(NE + 255) / 256, 256, 0, stream>>>(dst, i_deg);
  scan_deg<<<1, 1024, 0, stream>>>(i_deg, i_rowstart, i_cursor);
  fill_csr<<<(NE + 255) / 256, 256, 0, stream>>>(dst, i_cursor, i_elist);
  seg_sort<<<NN, 128, 0, stream>>>(i_rowstart, i_elist);
  perm_edges<<<(NE + 255) / 256, 256, 0, stream>>>(i_elist, src, dst, i_srcp, i_dstp);

  // ---- embeddings: h fp32; e single-bf16 directly in slot space ----
  gemm128<<<313, 256, 0, stream>>>(h_in, pw_h, pw_l, nb, f_h, NN);
  gemm128s<<<5000, 256, 0, stream>>>(eattr, i_elist, pw_h + 16384, pw_l + 16384, eb, e_bf);

  for (int l = 0; l < NL; ++l) {
    const unsigned short* lwh = pw_h + (long)(2 + l * 5) * 16384;
    const unsigned short* lwl = pw_l + (long)(2 + l * 5) * 16384;
    const float* bl = LB + (long)l * 5 * 128;
    int last = (l == NL - 1);

    gemm128_x4<<<dim3(313, 4), 256, 0, stream>>>(f_h, lwh, lwl, bl, f_A, b_B, b_D, b_E, NN);
    if (l == 0)
      edge_fused0<<<5000, 256, 0, stream>>>(e_bf, lwh + 2 * 16384, lwl + 2 * 16384,
                                            bl + 2 * 128, i_srcp, i_dstp, b_D, b_E,
                                            f_ehat, f_epart, 1);
    else if (l == 1)
      edge_fusedU<true><<<5000, 256, 0, stream>>>(e_bf, f_ehat,
                                                  f_stats + S_ESC, f_stats + S_ESH,
                                                  lwh + 2 * 16384, lwl + 2 * 16384, bl + 2 * 128,
                                                  i_srcp, i_dstp, b_D, b_E, f_epart, 1);
    else
      edge_fusedU<false><<<5000, 256, 0, stream>>>(e_bf, f_ehat,
                                                   f_stats + S_ESC, f_stats + S_ESH,
                                                   lwh + 2 * 16384, lwl + 2 * 16384, bl + 2 * 128,
                                                   i_srcp, i_dstp, b_D, b_E, f_epart, 0);
    if (!last) {
      reduce_part<<<50, 256, 0, stream>>>(f_epart, f_epart2, 100);
      finalize_bn_p<<<1, 128, 0, stream>>>(f_epart2, 50, 1.0f / NE,
                                           G + (l * 2 + 1) * 128, Bt + (l * 2 + 1) * 128,
                                           f_stats + S_ESC, f_stats + S_ESH);
    }
    gather_node<<<NN, 128, 0, stream>>>(f_ehat, b_B, i_srcp, i_rowstart, f_A);
    stats128p<<<250, 256, 0, stream>>>(f_A, f_npart);
    finalize_bn_p<<<1, 128, 0, stream>>>(f_npart, 250, 1.0f / NN,
                                         G + (l * 2 + 0) * 128, Bt + (l * 2 + 0) * 128,
                                         f_stats + S_NSC, f_stats + S_NSH);
    pass2<<<2500, 256, 0, stream>>>(f_h, f_A, f_stats + S_NSC, f_stats + S_NSH, (long)NN * 32);
  }

  colsum_p<<<250, 256, 0, stream>>>(f_h, f_hpart);
  cls_head<<<1, 128, 0, stream>>>(f_hpart, W1, b1, W2, b2, out);
}